// Round 11
// baseline (614.782 us; speedup 1.0000x reference)
//
#include <hip/hip_runtime.h>
#include <math.h>

#define B_ 8
#define T_ 12
#define N_ 200
#define R_ 1600    // B*N
#define NN_ 40000  // N*N

__device__ __forceinline__ float sigm(float v) { return 1.f / (1.f + expf(-v)); }

// ======== Phase A: dy-GRU chain + P/Q projections (bias folded into P) ====
__global__ void __launch_bounds__(256) k_dyall(
        const float* __restrict__ x,  const float* __restrict__ nf,
        const float* __restrict__ Ws2d, const float* __restrict__ bs2d,
        const float* __restrict__ Wrz,  const float* __restrict__ brz,
        const float* __restrict__ Wh,   const float* __restrict__ bh,
        const float* __restrict__ Wc2,  const float* __restrict__ Wm2,
        const float* __restrict__ bc2,  const float* __restrict__ bm2,
        float* __restrict__ Pc, float* __restrict__ Qc,
        float* __restrict__ Pm, float* __restrict__ Qm,
        float* __restrict__ state) {
    __shared__ float sWs2d[64 * 32], sWrz[33 * 64], sWh[33 * 32];
    __shared__ float sWc2[64 * 32], sWm2[64 * 32];
    __shared__ float sbrz[64], sbh[32], sbs2d[32], sbc2[32], sbm2[32];
    __shared__ float nfs[4][64], dy[4][32], in1[4][33], in2[4][33], rz[4][64], s4[4][32];
    int bk = blockIdx.x, tid = threadIdx.x;
    int w = tid >> 6, o = tid & 63;
    int row = bk * 4 + w, b = row / N_, n = row % N_;
    state[bk * 256 + tid] = 0.f;
    for (int idx = tid; idx < 2048; idx += 256) sWs2d[idx] = Ws2d[idx];
    for (int idx = tid; idx < 2112; idx += 256) sWrz[idx] = Wrz[idx];
    for (int idx = tid; idx < 1056; idx += 256) sWh[idx] = Wh[idx];
    for (int idx = tid; idx < 2048; idx += 256) { sWc2[idx] = Wc2[idx]; sWm2[idx] = Wm2[idx]; }
    if (tid < 64) sbrz[tid] = brz[tid];
    if (tid < 32) { sbh[tid] = bh[tid]; sbs2d[tid] = bs2d[tid];
                    sbc2[tid] = bc2[tid]; sbm2[tid] = bm2[tid]; }
    nfs[w][o] = nf[n * 64 + o];
    __syncthreads();
    if (o < 32) {
        float acc = sbs2d[o];
        #pragma unroll 8
        for (int i = 0; i < 64; ++i) acc += nfs[w][i] * sWs2d[i * 32 + o];
        dy[w][o] = acc;
    }
    __syncthreads();
    for (int t = 0; t < T_; ++t) {
        if (o == 0) { float v = x[((b * T_ + t) * N_ + n) * 2]; in1[w][0] = v; in2[w][0] = v; }
        if (o < 32) in1[w][o + 1] = dy[w][o];
        __syncthreads();
        float acc = sbrz[o];
        #pragma unroll
        for (int i = 0; i < 33; ++i) acc += in1[w][i] * sWrz[i * 64 + o];
        rz[w][o] = sigm(acc);
        __syncthreads();
        if (o < 32) in2[w][o + 1] = rz[w][o] * dy[w][o];
        __syncthreads();
        if (o < 32) {
            float h = sbh[o];
            #pragma unroll
            for (int i = 0; i < 33; ++i) h += in2[w][i] * sWh[i * 32 + o];
            h = tanhf(h);
            float z = rz[w][32 + o];
            float nd = z * dy[w][o] + (1.f - z) * h;
            dy[w][o] = nd;
            s4[w][o] = nd > 0.f ? nd : 0.f;
        }
        __syncthreads();
        size_t base = ((size_t)t * R_ + row) * 32;
        for (int idx = o; idx < 128; idx += 64) {
            int mat = idx >> 5, k = idx & 31;
            const float* W = (mat < 2) ? sWc2 : sWm2;
            int rb = (mat & 1) ? 32 : 0;
            float a = (mat == 0) ? sbc2[k] : (mat == 2) ? sbm2[k] : 0.f;
            #pragma unroll
            for (int i = 0; i < 32; ++i) a += s4[w][i] * W[(rb + i) * 32 + k];
            ((mat == 0) ? Pc : (mat == 1) ? Qc : (mat == 2) ? Pm : Qm)[base + k] = a;
        }
        __syncthreads();
    }
}

// ======== Phase B: all 96 adjacency matrices (R8 scalar inner, bias folded) =
__global__ void __launch_bounds__(256) k_pairall(
        const float* __restrict__ Pc, const float* __restrict__ Qc,
        const float* __restrict__ Pm, const float* __restrict__ Qm,
        const float* __restrict__ Wc1, const float* __restrict__ bc1,
        const float* __restrict__ Wm1, const float* __restrict__ bm1,
        float* __restrict__ out) {
    __shared__ float sPc[16][33], sQc[16][33], sPm[16][33], sQm[16][33];
    __shared__ float sWc1[32], sWm1[32];
    int z = blockIdx.z;            // t*8 + b
    int i0 = blockIdx.x * 16, j0 = blockIdx.y * 16;
    int tid = threadIdx.y * 16 + threadIdx.x;
    size_t tb = (size_t)z * N_;
    for (int l = tid; l < 512; l += 256) {
        int r = l >> 5, k = l & 31;
        int gi = i0 + r, gj = j0 + r;
        sPc[r][k] = (gi < N_) ? Pc[(tb + gi) * 32 + k] : 0.f;
        sPm[r][k] = (gi < N_) ? Pm[(tb + gi) * 32 + k] : 0.f;
        sQc[r][k] = (gj < N_) ? Qc[(tb + gj) * 32 + k] : 0.f;
        sQm[r][k] = (gj < N_) ? Qm[(tb + gj) * 32 + k] : 0.f;
    }
    if (tid < 32) { sWc1[tid] = Wc1[tid]; sWm1[tid] = Wm1[tid]; }
    __syncthreads();
    int i = i0 + threadIdx.y, j = j0 + threadIdx.x;
    if (i >= N_ || j >= N_) return;
    float g = 0.f, m = 0.f;
    #pragma unroll
    for (int k = 0; k < 32; ++k) {
        float hc = sPc[threadIdx.y][k] + sQc[threadIdx.x][k];   // bias in Pc
        g += (hc > 0.f ? hc : 0.f) * sWc1[k];
        float hm = sPm[threadIdx.y][k] + sQm[threadIdx.x][k];
        m += (hm > 0.f ? hm : 0.f) * sWm1[k];
    }
    g += bc1[0];
    m += bm1[0];
    out[R_ + (((size_t)z * N_ + i) * N_ + j)] = g * sigm(m);
}

// ======== A2 = A @ A: 128x128 tile, 8x8 microtile (LDS-cycles per output /4) =
__global__ void __launch_bounds__(256) k_a2(
        const float* __restrict__ Abase, float* __restrict__ Cbase, int nmat) {
    __shared__ float Ast[32][132];  // [k][i] transposed
    __shared__ float Bs[32][132];   // [k][j]
    int bx = blockIdx.x;
    int z = bx % nmat, tl = bx / nmat;    // tl in 0..3
    int i0 = (tl >> 1) * 128, j0 = (tl & 1) * 128;
    const float* Az = Abase + (size_t)z * NN_;
    float* Cz = Cbase + (size_t)z * NN_;
    int tid = threadIdx.x;
    int tx = tid & 15, ty = tid >> 4;
    float acc[8][8] = {};
    for (int k0 = 0; k0 < 200; k0 += 32) {
        for (int idx = tid; idx < 4096; idx += 256) {
            int i = idx >> 5, k = idx & 31;
            Ast[k][i] = (i0 + i < 200 && k0 + k < 200) ? Az[(i0 + i) * 200 + k0 + k] : 0.f;
        }
        for (int idx = tid; idx < 4096; idx += 256) {
            int k = idx >> 7, j = idx & 127;
            Bs[k][j] = (k0 + k < 200 && j0 + j < 200) ? Az[(k0 + k) * 200 + j0 + j] : 0.f;
        }
        __syncthreads();
        #pragma unroll 4
        for (int k = 0; k < 32; ++k) {
            float4 a0 = *(const float4*)&Ast[k][ty * 8];
            float4 a1 = *(const float4*)&Ast[k][ty * 8 + 4];
            float4 b0 = *(const float4*)&Bs[k][tx * 8];
            float4 b1 = *(const float4*)&Bs[k][tx * 8 + 4];
            float av[8] = { a0.x, a0.y, a0.z, a0.w, a1.x, a1.y, a1.z, a1.w };
            float bv[8] = { b0.x, b0.y, b0.z, b0.w, b1.x, b1.y, b1.z, b1.w };
            #pragma unroll
            for (int ii = 0; ii < 8; ++ii)
                #pragma unroll
                for (int jj = 0; jj < 8; ++jj)
                    acc[ii][jj] += av[ii] * bv[jj];
        }
        __syncthreads();
    }
    #pragma unroll
    for (int ii = 0; ii < 8; ++ii) {
        int gi = i0 + ty * 8 + ii;
        if (gi >= 200) break;
        #pragma unroll
        for (int jj = 0; jj < 8; ++jj) {
            int gj = j0 + tx * 8 + jj;
            if (gj < 200) Cz[(size_t)gi * 200 + gj] = acc[ii][jj];
        }
    }
}

// ======== xt-hops: xh[zl][i][4] = {A@x0, A@x1, A2@x0, A2@x1} ========
__global__ void __launch_bounds__(256) k_xh(
        const float* __restrict__ Abase, const float* __restrict__ A2base,
        const float* __restrict__ x, int z0, float* __restrict__ xh) {
    __shared__ float xtl[400];
    int zl = blockIdx.x, tid = threadIdx.x;
    int z = z0 + zl, t = z >> 3, b = z & 7;
    int w = tid >> 6, l = tid & 63;
    const float* xb = x + ((size_t)(b * T_ + t)) * N_ * 2;
    for (int idx = tid; idx < 400; idx += 256) xtl[idx] = xb[idx];
    __syncthreads();
    for (int it = 0; it < 50; ++it) {
        int i = it * 4 + w;
        float p0 = 0.f, p1 = 0.f, p2 = 0.f, p3 = 0.f;
        if (l < 50) {
            float4 a4 = *(const float4*)(Abase + (size_t)zl * NN_ + i * 200 + 4 * l);
            float4 c4 = *(const float4*)(A2base + (size_t)zl * NN_ + i * 200 + 4 * l);
            #pragma unroll
            for (int q = 0; q < 4; ++q) {
                float av = (&a4.x)[q], cv = (&c4.x)[q];
                float x0 = xtl[(4 * l + q) * 2], x1 = xtl[(4 * l + q) * 2 + 1];
                p0 += av * x0; p1 += av * x1; p2 += cv * x0; p3 += cv * x1;
            }
        }
        #pragma unroll
        for (int off = 32; off > 0; off >>= 1) {
            p0 += __shfl_down(p0, off); p1 += __shfl_down(p1, off);
            p2 += __shfl_down(p2, off); p3 += __shfl_down(p3, off);
        }
        if (l == 0) *(float4*)(xh + ((size_t)zl * N_ + i) * 4) = make_float4(p0, p1, p2, p3);
    }
}

// ======== K1: hops + ru gate -> rs, u (4 rows/block, 400 blocks) ========
__global__ void __launch_bounds__(256) k_ru2(
        const float* __restrict__ At, const float* __restrict__ A2t,
        const float* __restrict__ xht,
        const float* __restrict__ x, int t, const float* __restrict__ state,
        const float* __restrict__ Wru, const float* __restrict__ bru,
        float* __restrict__ rs, float* __restrict__ ub) {
    __shared__ float sF[200 * 64];
    __shared__ float a4s[4 * 200], c4s[4 * 200];
    __shared__ float g8[4 * 132];
    __shared__ float xts[8];
    int bx = blockIdx.x;
    int b = bx & 7, i0 = (bx >> 3) * 4;      // XCD-local batches
    int tid = threadIdx.x;
    {
        const float4* stb = (const float4*)(state + (size_t)b * N_ * 64);
        float4* sFv = (float4*)sF;
        for (int idx = tid; idx < 3200; idx += 256) sFv[idx] = stb[idx];
        const float4* Ar = (const float4*)(At + ((size_t)b * N_ + i0) * 200);
        const float4* Cr = (const float4*)(A2t + ((size_t)b * N_ + i0) * 200);
        float4* av = (float4*)a4s; float4* cv = (float4*)c4s;
        for (int idx = tid; idx < 200; idx += 256) { av[idx] = Ar[idx]; cv[idx] = Cr[idx]; }
        if (tid < 8) xts[tid] = x[((size_t)(b * T_ + t) * N_ + i0 + (tid >> 1)) * 2 + (tid & 1)];
        if (tid >= 8 && tid < 24) {
            int l = tid - 8, rr = l >> 2, q = l & 3;
            g8[rr * 132 + ((q < 2) ? q : q + 64)] = xht[((size_t)b * N_ + i0 + rr) * 4 + q];
        }
    }
    __syncthreads();
    if (tid < 64) {   // hop: r=tid>>4 (0..3), cg=tid&15 (4 cols), BOTH matrices
        int r = tid >> 4, cg = tid & 15;
        const float* ar = a4s + r * 200;
        const float* cr = c4s + r * 200;
        float4 accA = make_float4(0.f, 0.f, 0.f, 0.f);
        float4 accC = make_float4(0.f, 0.f, 0.f, 0.f);
        #pragma unroll 2
        for (int jg = 0; jg < 50; ++jg) {
            float4 a4 = *(const float4*)&ar[4 * jg];
            float4 c4 = *(const float4*)&cr[4 * jg];
            const float* fb = &sF[(4 * jg) * 64 + 4 * cg];
            float4 v0 = *(const float4*)fb;
            float4 v1 = *(const float4*)(fb + 64);
            float4 v2 = *(const float4*)(fb + 128);
            float4 v3 = *(const float4*)(fb + 192);
            accA.x += a4.x * v0.x + a4.y * v1.x + a4.z * v2.x + a4.w * v3.x;
            accA.y += a4.x * v0.y + a4.y * v1.y + a4.z * v2.y + a4.w * v3.y;
            accA.z += a4.x * v0.z + a4.y * v1.z + a4.z * v2.z + a4.w * v3.z;
            accA.w += a4.x * v0.w + a4.y * v1.w + a4.z * v2.w + a4.w * v3.w;
            accC.x += c4.x * v0.x + c4.y * v1.x + c4.z * v2.x + c4.w * v3.x;
            accC.y += c4.x * v0.y + c4.y * v1.y + c4.z * v2.y + c4.w * v3.y;
            accC.z += c4.x * v0.z + c4.y * v1.z + c4.z * v2.z + c4.w * v3.z;
            accC.w += c4.x * v0.w + c4.y * v1.w + c4.z * v2.w + c4.w * v3.w;
        }
        float* gr = &g8[r * 132 + 2 + 4 * cg];
        gr[0] = accA.x; gr[1] = accA.y; gr[2] = accA.z; gr[3] = accA.w;
        float* gr2 = gr + 66;
        gr2[0] = accC.x; gr2[1] = accC.y; gr2[2] = accC.z; gr2[3] = accC.w;
    }
    __syncthreads();
    {   // gate: c=tid&127, rq=tid>>7 (0..1) -> rows rq*2+{0,1}
        int c = tid & 127, rq = tid >> 7;
        int r0 = rq * 2, r1 = r0 + 1;
        float bv = bru[c];
        float a0 = bv, a1 = bv;
        #pragma unroll
        for (int k = 0; k < 2; ++k) {
            float wv = Wru[k * 128 + c];
            a0 += xts[r0 * 2 + k] * wv;
            a1 += xts[r1 * 2 + k] * wv;
        }
        #pragma unroll 4
        for (int kg = 0; kg < 16; ++kg) {
            float4 f0 = *(const float4*)&sF[(i0 + r0) * 64 + 4 * kg];
            float4 f1 = *(const float4*)&sF[(i0 + r1) * 64 + 4 * kg];
            const float* Wp = Wru + (2 + 4 * kg) * 128 + c;
            float w0 = Wp[0], w1 = Wp[128], w2 = Wp[256], w3 = Wp[384];
            a0 += f0.x * w0 + f0.y * w1 + f0.z * w2 + f0.w * w3;
            a1 += f1.x * w0 + f1.y * w1 + f1.z * w2 + f1.w * w3;
        }
        #pragma unroll 4
        for (int kg = 0; kg < 33; ++kg) {
            float4 f0 = *(const float4*)&g8[r0 * 132 + 4 * kg];
            float4 f1 = *(const float4*)&g8[r1 * 132 + 4 * kg];
            const float* Wp = Wru + (66 + 4 * kg) * 128 + c;
            float w0 = Wp[0], w1 = Wp[128], w2 = Wp[256], w3 = Wp[384];
            a0 += f0.x * w0 + f0.y * w1 + f0.z * w2 + f0.w * w3;
            a1 += f1.x * w0 + f1.y * w1 + f1.z * w2 + f1.w * w3;
        }
        float v0 = sigm(a0), v1 = sigm(a1);
        size_t gr0 = (size_t)b * N_ + i0 + r0, gr1 = gr0 + 1;
        if (c < 64) {
            rs[gr0 * 64 + c] = v0 * sF[(i0 + r0) * 64 + c];
            rs[gr1 * 64 + c] = v1 * sF[(i0 + r1) * 64 + c];
        } else {
            ub[gr0 * 64 + (c - 64)] = v0;
            ub[gr1 * 64 + (c - 64)] = v1;
        }
    }
}

// ======== K2: hops + cand gate + state update (4 rows/block) ========
__global__ void __launch_bounds__(256) k_cand2(
        const float* __restrict__ At, const float* __restrict__ A2t,
        const float* __restrict__ xht,
        const float* __restrict__ x, int t, const float* __restrict__ rsin,
        const float* __restrict__ Wcd, const float* __restrict__ bcd,
        const float* __restrict__ ub, float* __restrict__ state) {
    __shared__ float sF[200 * 64];
    __shared__ float a4s[4 * 200], c4s[4 * 200];
    __shared__ float g8[4 * 132];
    __shared__ float xts[8];
    int bx = blockIdx.x;
    int b = bx & 7, i0 = (bx >> 3) * 4;      // XCD-local batches
    int tid = threadIdx.x;
    {
        const float4* rbv = (const float4*)(rsin + (size_t)b * N_ * 64);
        float4* sFv = (float4*)sF;
        for (int idx = tid; idx < 3200; idx += 256) sFv[idx] = rbv[idx];
        const float4* Ar = (const float4*)(At + ((size_t)b * N_ + i0) * 200);
        const float4* Cr = (const float4*)(A2t + ((size_t)b * N_ + i0) * 200);
        float4* av = (float4*)a4s; float4* cv = (float4*)c4s;
        for (int idx = tid; idx < 200; idx += 256) { av[idx] = Ar[idx]; cv[idx] = Cr[idx]; }
        if (tid < 8) xts[tid] = x[((size_t)(b * T_ + t) * N_ + i0 + (tid >> 1)) * 2 + (tid & 1)];
        if (tid >= 8 && tid < 24) {
            int l = tid - 8, rr = l >> 2, q = l & 3;
            g8[rr * 132 + ((q < 2) ? q : q + 64)] = xht[((size_t)b * N_ + i0 + rr) * 4 + q];
        }
    }
    __syncthreads();
    if (tid < 64) {   // hop, both matrices
        int r = tid >> 4, cg = tid & 15;
        const float* ar = a4s + r * 200;
        const float* cr = c4s + r * 200;
        float4 accA = make_float4(0.f, 0.f, 0.f, 0.f);
        float4 accC = make_float4(0.f, 0.f, 0.f, 0.f);
        #pragma unroll 2
        for (int jg = 0; jg < 50; ++jg) {
            float4 a4 = *(const float4*)&ar[4 * jg];
            float4 c4 = *(const float4*)&cr[4 * jg];
            const float* fb = &sF[(4 * jg) * 64 + 4 * cg];
            float4 v0 = *(const float4*)fb;
            float4 v1 = *(const float4*)(fb + 64);
            float4 v2 = *(const float4*)(fb + 128);
            float4 v3 = *(const float4*)(fb + 192);
            accA.x += a4.x * v0.x + a4.y * v1.x + a4.z * v2.x + a4.w * v3.x;
            accA.y += a4.x * v0.y + a4.y * v1.y + a4.z * v2.y + a4.w * v3.y;
            accA.z += a4.x * v0.z + a4.y * v1.z + a4.z * v2.z + a4.w * v3.z;
            accA.w += a4.x * v0.w + a4.y * v1.w + a4.z * v2.w + a4.w * v3.w;
            accC.x += c4.x * v0.x + c4.y * v1.x + c4.z * v2.x + c4.w * v3.x;
            accC.y += c4.x * v0.y + c4.y * v1.y + c4.z * v2.y + c4.w * v3.y;
            accC.z += c4.x * v0.z + c4.y * v1.z + c4.z * v2.z + c4.w * v3.z;
            accC.w += c4.x * v0.w + c4.y * v1.w + c4.z * v2.w + c4.w * v3.w;
        }
        float* gr = &g8[r * 132 + 2 + 4 * cg];
        gr[0] = accA.x; gr[1] = accA.y; gr[2] = accA.z; gr[3] = accA.w;
        float* gr2 = gr + 66;
        gr2[0] = accC.x; gr2[1] = accC.y; gr2[2] = accC.z; gr2[3] = accC.w;
    }
    __syncthreads();
    {   // gate: r=tid>>6 (0..3), c=tid&63 — one output each
        int c = tid & 63, r = tid >> 6;
        float a0 = bcd[c];
        #pragma unroll
        for (int k = 0; k < 2; ++k) a0 += xts[r * 2 + k] * Wcd[k * 64 + c];
        #pragma unroll 4
        for (int kg = 0; kg < 16; ++kg) {
            float4 f0 = *(const float4*)&sF[(i0 + r) * 64 + 4 * kg];
            const float* Wp = Wcd + (2 + 4 * kg) * 64 + c;
            a0 += f0.x * Wp[0] + f0.y * Wp[64] + f0.z * Wp[128] + f0.w * Wp[192];
        }
        #pragma unroll 4
        for (int kg = 0; kg < 33; ++kg) {
            float4 f0 = *(const float4*)&g8[r * 132 + 4 * kg];
            const float* Wp = Wcd + (66 + 4 * kg) * 64 + c;
            a0 += f0.x * Wp[0] + f0.y * Wp[64] + f0.z * Wp[128] + f0.w * Wp[192];
        }
        size_t gr = (size_t)b * N_ + i0 + r;
        float cnd = tanhf(a0);
        float u = ub[gr * 64 + c];
        float st = state[gr * 64 + c];
        state[gr * 64 + c] = u * st + (1.f - u) * cnd;
    }
}

// ======== pred head ========
__global__ void __launch_bounds__(64) k_pred(
        const float* __restrict__ state,
        const float* __restrict__ Wp1, const float* __restrict__ bp1,
        const float* __restrict__ Wp2, const float* __restrict__ bp2,
        float* __restrict__ out) {
    __shared__ float st[64];
    int row = blockIdx.x;
    int tid = threadIdx.x;
    st[tid] = state[row * 64 + tid];
    __syncthreads();
    float acc = bp1[tid];
    #pragma unroll 8
    for (int a = 0; a < 64; ++a) acc += st[a] * Wp1[a * 64 + tid];
    acc = acc > 0.f ? acc : 0.01f * acc;
    float v = acc * Wp2[tid];
    #pragma unroll
    for (int off = 32; off > 0; off >>= 1) v += __shfl_down(v, off);
    if (tid == 0) out[row] = v + bp2[0];
}

extern "C" void kernel_launch(void* const* d_in, const int* in_sizes, int n_in,
                              void* d_out, int out_size, void* d_ws, size_t ws_size,
                              hipStream_t stream) {
    const float* x    = (const float*)d_in[0];
    const float* nf   = (const float*)d_in[1];
    const float* Ws2d = (const float*)d_in[2];
    const float* bs2d = (const float*)d_in[3];
    const float* Wrz  = (const float*)d_in[4];
    const float* brz  = (const float*)d_in[5];
    const float* Wh   = (const float*)d_in[6];
    const float* bh   = (const float*)d_in[7];
    const float* Wc2  = (const float*)d_in[8];
    const float* bc2  = (const float*)d_in[9];
    const float* Wc1  = (const float*)d_in[10];
    const float* bc1  = (const float*)d_in[11];
    const float* Wm2  = (const float*)d_in[12];
    const float* bm2  = (const float*)d_in[13];
    const float* Wm1  = (const float*)d_in[14];
    const float* bm1  = (const float*)d_in[15];
    const float* Wru  = (const float*)d_in[16];
    const float* bru  = (const float*)d_in[17];
    const float* Wcand= (const float*)d_in[18];
    const float* bcand= (const float*)d_in[19];
    const float* Wp1  = (const float*)d_in[20];
    const float* bp1  = (const float*)d_in[21];
    const float* Wp2  = (const float*)d_in[22];
    const float* bp2  = (const float*)d_in[23];
    float* out = (float*)d_out;

    float* ws = (float*)d_ws;
    const size_t PQ = (size_t)T_ * R_ * 32;
    float* Pc = ws;
    float* Qc = Pc + PQ;
    float* Pm = Qc + PQ;
    float* Qm = Pm + PQ;

    const size_t A2F = (size_t)96 * NN_;
    const size_t XHF = (size_t)96 * N_ * 4;
    const size_t FULL_NEED = (A2F + XHF + 3 * (size_t)R_ * 64) * 4;
    bool full = ws_size >= FULL_NEED;

    const float* Aall = out + R_;

    if (full) {
        float* A2base = ws;                  // aliases dead P/Q after k_pairall
        float* xhbase = ws + A2F;
        float* state  = xhbase + XHF;
        float* rs     = state + (size_t)R_ * 64;
        float* ub     = rs + (size_t)R_ * 64;

        k_dyall<<<400, 256, 0, stream>>>(x, nf, Ws2d, bs2d, Wrz, brz, Wh, bh,
                                         Wc2, Wm2, bc2, bm2, Pc, Qc, Pm, Qm, state);
        k_pairall<<<dim3(13, 13, 96), dim3(16, 16), 0, stream>>>(
            Pc, Qc, Pm, Qm, Wc1, bc1, Wm1, bm1, out);
        k_a2<<<96 * 4, 256, 0, stream>>>(Aall, A2base, 96);
        k_xh<<<96, 256, 0, stream>>>(Aall, A2base, x, 0, xhbase);

        for (int t = 0; t < T_; ++t) {
            const float* At  = Aall + (size_t)t * 8 * NN_;
            const float* A2t = A2base + (size_t)t * 8 * NN_;
            const float* xht = xhbase + (size_t)t * 8 * N_ * 4;
            k_ru2  <<<400, 256, 0, stream>>>(At, A2t, xht, x, t, state, Wru, bru, rs, ub);
            k_cand2<<<400, 256, 0, stream>>>(At, A2t, xht, x, t, rs, Wcand, bcand, ub, state);
        }
        k_pred<<<R_, 64, 0, stream>>>(state, Wp1, bp1, Wp2, bp2, out);
    } else {
        float* A2base = ws + 4 * PQ;
        float* xhbase = A2base + (size_t)8 * NN_;
        float* state  = xhbase + (size_t)8 * N_ * 4;
        float* rs     = state + (size_t)R_ * 64;
        float* ub     = rs + (size_t)R_ * 64;

        k_dyall<<<400, 256, 0, stream>>>(x, nf, Ws2d, bs2d, Wrz, brz, Wh, bh,
                                         Wc2, Wm2, bc2, bm2, Pc, Qc, Pm, Qm, state);
        k_pairall<<<dim3(13, 13, 96), dim3(16, 16), 0, stream>>>(
            Pc, Qc, Pm, Qm, Wc1, bc1, Wm1, bm1, out);
        for (int t = 0; t < T_; ++t) {
            const float* At = Aall + (size_t)t * 8 * NN_;
            k_a2<<<8 * 4, 256, 0, stream>>>(At, A2base, 8);
            k_xh<<<8, 256, 0, stream>>>(At, A2base, x, t * 8, xhbase);
            k_ru2  <<<400, 256, 0, stream>>>(At, A2base, xhbase, x, t, state, Wru, bru, rs, ub);
            k_cand2<<<400, 256, 0, stream>>>(At, A2base, xhbase, x, t, rs, Wcand, bcand, ub, state);
        }
        k_pred<<<R_, 64, 0, stream>>>(state, Wp1, bp1, Wp2, bp2, out);
    }
}

// Round 12
// 566.741 us; speedup vs baseline: 1.0848x; 1.0848x over previous
//
#include <hip/hip_runtime.h>
#include <math.h>

#define B_ 8
#define T_ 12
#define N_ 200
#define R_ 1600    // B*N
#define NN_ 40000  // N*N

__device__ __forceinline__ float sigm(float v) { return 1.f / (1.f + expf(-v)); }

// ======== Phase A: dy-GRU chain + P/Q projections (bias folded into P) ====
__global__ void __launch_bounds__(256) k_dyall(
        const float* __restrict__ x,  const float* __restrict__ nf,
        const float* __restrict__ Ws2d, const float* __restrict__ bs2d,
        const float* __restrict__ Wrz,  const float* __restrict__ brz,
        const float* __restrict__ Wh,   const float* __restrict__ bh,
        const float* __restrict__ Wc2,  const float* __restrict__ Wm2,
        const float* __restrict__ bc2,  const float* __restrict__ bm2,
        float* __restrict__ Pc, float* __restrict__ Qc,
        float* __restrict__ Pm, float* __restrict__ Qm,
        float* __restrict__ state) {
    __shared__ float sWs2d[64 * 32], sWrz[33 * 64], sWh[33 * 32];
    __shared__ float sWc2[64 * 32], sWm2[64 * 32];
    __shared__ float sbrz[64], sbh[32], sbs2d[32], sbc2[32], sbm2[32];
    __shared__ float nfs[4][64], dy[4][32], in1[4][33], in2[4][33], rz[4][64], s4[4][32];
    int bk = blockIdx.x, tid = threadIdx.x;
    int w = tid >> 6, o = tid & 63;
    int row = bk * 4 + w, b = row / N_, n = row % N_;
    state[bk * 256 + tid] = 0.f;
    for (int idx = tid; idx < 2048; idx += 256) sWs2d[idx] = Ws2d[idx];
    for (int idx = tid; idx < 2112; idx += 256) sWrz[idx] = Wrz[idx];
    for (int idx = tid; idx < 1056; idx += 256) sWh[idx] = Wh[idx];
    for (int idx = tid; idx < 2048; idx += 256) { sWc2[idx] = Wc2[idx]; sWm2[idx] = Wm2[idx]; }
    if (tid < 64) sbrz[tid] = brz[tid];
    if (tid < 32) { sbh[tid] = bh[tid]; sbs2d[tid] = bs2d[tid];
                    sbc2[tid] = bc2[tid]; sbm2[tid] = bm2[tid]; }
    nfs[w][o] = nf[n * 64 + o];
    __syncthreads();
    if (o < 32) {
        float acc = sbs2d[o];
        #pragma unroll 8
        for (int i = 0; i < 64; ++i) acc += nfs[w][i] * sWs2d[i * 32 + o];
        dy[w][o] = acc;
    }
    __syncthreads();
    for (int t = 0; t < T_; ++t) {
        if (o == 0) { float v = x[((b * T_ + t) * N_ + n) * 2]; in1[w][0] = v; in2[w][0] = v; }
        if (o < 32) in1[w][o + 1] = dy[w][o];
        __syncthreads();
        float acc = sbrz[o];
        #pragma unroll
        for (int i = 0; i < 33; ++i) acc += in1[w][i] * sWrz[i * 64 + o];
        rz[w][o] = sigm(acc);
        __syncthreads();
        if (o < 32) in2[w][o + 1] = rz[w][o] * dy[w][o];
        __syncthreads();
        if (o < 32) {
            float h = sbh[o];
            #pragma unroll
            for (int i = 0; i < 33; ++i) h += in2[w][i] * sWh[i * 32 + o];
            h = tanhf(h);
            float z = rz[w][32 + o];
            float nd = z * dy[w][o] + (1.f - z) * h;
            dy[w][o] = nd;
            s4[w][o] = nd > 0.f ? nd : 0.f;
        }
        __syncthreads();
        size_t base = ((size_t)t * R_ + row) * 32;
        for (int idx = o; idx < 128; idx += 64) {
            int mat = idx >> 5, k = idx & 31;
            const float* W = (mat < 2) ? sWc2 : sWm2;
            int rb = (mat & 1) ? 32 : 0;
            float a = (mat == 0) ? sbc2[k] : (mat == 2) ? sbm2[k] : 0.f;
            #pragma unroll
            for (int i = 0; i < 32; ++i) a += s4[w][i] * W[(rb + i) * 32 + k];
            ((mat == 0) ? Pc : (mat == 1) ? Qc : (mat == 2) ? Pm : Qm)[base + k] = a;
        }
        __syncthreads();
    }
}

// ======== Phase B: adjacency matrices — float4 LDS reads, stride-36 pad ====
__global__ void __launch_bounds__(256) k_pairall(
        const float* __restrict__ Pc, const float* __restrict__ Qc,
        const float* __restrict__ Pm, const float* __restrict__ Qm,
        const float* __restrict__ Wc1, const float* __restrict__ bc1,
        const float* __restrict__ Wm1, const float* __restrict__ bm1,
        float* __restrict__ out) {
    __shared__ float sPc[16][36], sQc[16][36], sPm[16][36], sQm[16][36];
    __shared__ float sWc1[32], sWm1[32];
    int z = blockIdx.z;            // t*8 + b
    int i0 = blockIdx.x * 16, j0 = blockIdx.y * 16;
    int tid = threadIdx.y * 16 + threadIdx.x;
    size_t tb = (size_t)z * N_;
    for (int l = tid; l < 128; l += 256) {   // 16 rows x 8 float4
        int r = l >> 3, q = l & 7;
        int gi = i0 + r, gj = j0 + r;
        float4 z4 = make_float4(0.f, 0.f, 0.f, 0.f);
        *(float4*)&sPc[r][4 * q] = (gi < N_) ? *(const float4*)&Pc[(tb + gi) * 32 + 4 * q] : z4;
        *(float4*)&sPm[r][4 * q] = (gi < N_) ? *(const float4*)&Pm[(tb + gi) * 32 + 4 * q] : z4;
        *(float4*)&sQc[r][4 * q] = (gj < N_) ? *(const float4*)&Qc[(tb + gj) * 32 + 4 * q] : z4;
        *(float4*)&sQm[r][4 * q] = (gj < N_) ? *(const float4*)&Qm[(tb + gj) * 32 + 4 * q] : z4;
    }
    if (tid < 32) { sWc1[tid] = Wc1[tid]; sWm1[tid] = Wm1[tid]; }
    __syncthreads();
    int i = i0 + threadIdx.y, j = j0 + threadIdx.x;
    if (i >= N_ || j >= N_) return;
    int ty = threadIdx.y, tx = threadIdx.x;
    float g0 = 0.f, g1 = 0.f, m0 = 0.f, m1 = 0.f;
    #pragma unroll
    for (int kg = 0; kg < 8; ++kg) {
        float4 pc = *(const float4*)&sPc[ty][4 * kg];
        float4 qc = *(const float4*)&sQc[tx][4 * kg];
        float4 wc = *(const float4*)&sWc1[4 * kg];
        g0 += fmaxf(pc.x + qc.x, 0.f) * wc.x + fmaxf(pc.y + qc.y, 0.f) * wc.y;
        g1 += fmaxf(pc.z + qc.z, 0.f) * wc.z + fmaxf(pc.w + qc.w, 0.f) * wc.w;
        float4 pm = *(const float4*)&sPm[ty][4 * kg];
        float4 qm = *(const float4*)&sQm[tx][4 * kg];
        float4 wm = *(const float4*)&sWm1[4 * kg];
        m0 += fmaxf(pm.x + qm.x, 0.f) * wm.x + fmaxf(pm.y + qm.y, 0.f) * wm.y;
        m1 += fmaxf(pm.z + qm.z, 0.f) * wm.z + fmaxf(pm.w + qm.w, 0.f) * wm.w;
    }
    float g = g0 + g1 + bc1[0];
    float m = m0 + m1 + bm1[0];
    out[R_ + (((size_t)z * N_ + i) * N_ + j)] = g * sigm(m);
}

// ======== A2 = A @ A, 64-tile GEMM (reverted to R9/R10 version) ========
__global__ void __launch_bounds__(256) k_a2(
        const float* __restrict__ Abase, float* __restrict__ Cbase, int nmat) {
    __shared__ float Ast[32][68];   // [k][i]
    __shared__ float Bs[32][68];    // [k][j]
    int bx = blockIdx.x;
    int z = bx % nmat, tl = bx / nmat;
    int i0 = (tl >> 2) * 64, j0 = (tl & 3) * 64;
    const float* Az = Abase + (size_t)z * NN_;
    float* Cz = Cbase + (size_t)z * NN_;
    int tid = threadIdx.x;
    int tx = tid & 15, ty = tid >> 4;
    float acc[4][4] = {};
    for (int k0 = 0; k0 < 200; k0 += 32) {
        for (int idx = tid; idx < 2048; idx += 256) {
            int i = idx >> 5, k = idx & 31;
            Ast[k][i] = (i0 + i < 200 && k0 + k < 200) ? Az[(i0 + i) * 200 + k0 + k] : 0.f;
        }
        for (int idx = tid; idx < 2048; idx += 256) {
            int k = idx >> 6, j = idx & 63;
            Bs[k][j] = (k0 + k < 200 && j0 + j < 200) ? Az[(k0 + k) * 200 + j0 + j] : 0.f;
        }
        __syncthreads();
        #pragma unroll 8
        for (int k = 0; k < 32; ++k) {
            float4 av = *(const float4*)&Ast[k][ty * 4];
            float4 bv = *(const float4*)&Bs[k][tx * 4];
            acc[0][0] += av.x * bv.x; acc[0][1] += av.x * bv.y; acc[0][2] += av.x * bv.z; acc[0][3] += av.x * bv.w;
            acc[1][0] += av.y * bv.x; acc[1][1] += av.y * bv.y; acc[1][2] += av.y * bv.z; acc[1][3] += av.y * bv.w;
            acc[2][0] += av.z * bv.x; acc[2][1] += av.z * bv.y; acc[2][2] += av.z * bv.z; acc[2][3] += av.z * bv.w;
            acc[3][0] += av.w * bv.x; acc[3][1] += av.w * bv.y; acc[3][2] += av.w * bv.z; acc[3][3] += av.w * bv.w;
        }
        __syncthreads();
    }
    #pragma unroll
    for (int i = 0; i < 4; ++i) {
        int gi = i0 + ty * 4 + i;
        if (gi >= 200) break;
        #pragma unroll
        for (int j = 0; j < 4; ++j) {
            int gj = j0 + tx * 4 + j;
            if (gj < 200) Cz[gi * 200 + gj] = acc[i][j];
        }
    }
}

// ======== xt-hops: xh[zl][i][4] = {A@x0, A@x1, A2@x0, A2@x1} ========
__global__ void __launch_bounds__(256) k_xh(
        const float* __restrict__ Abase, const float* __restrict__ A2base,
        const float* __restrict__ x, int z0, float* __restrict__ xh) {
    __shared__ float xtl[400];
    int zl = blockIdx.x, tid = threadIdx.x;
    int z = z0 + zl, t = z >> 3, b = z & 7;
    int w = tid >> 6, l = tid & 63;
    const float* xb = x + ((size_t)(b * T_ + t)) * N_ * 2;
    for (int idx = tid; idx < 400; idx += 256) xtl[idx] = xb[idx];
    __syncthreads();
    for (int it = 0; it < 50; ++it) {
        int i = it * 4 + w;
        float p0 = 0.f, p1 = 0.f, p2 = 0.f, p3 = 0.f;
        if (l < 50) {
            float4 a4 = *(const float4*)(Abase + (size_t)zl * NN_ + i * 200 + 4 * l);
            float4 c4 = *(const float4*)(A2base + (size_t)zl * NN_ + i * 200 + 4 * l);
            #pragma unroll
            for (int q = 0; q < 4; ++q) {
                float av = (&a4.x)[q], cv = (&c4.x)[q];
                float x0 = xtl[(4 * l + q) * 2], x1 = xtl[(4 * l + q) * 2 + 1];
                p0 += av * x0; p1 += av * x1; p2 += cv * x0; p3 += cv * x1;
            }
        }
        #pragma unroll
        for (int off = 32; off > 0; off >>= 1) {
            p0 += __shfl_down(p0, off); p1 += __shfl_down(p1, off);
            p2 += __shfl_down(p2, off); p3 += __shfl_down(p3, off);
        }
        if (l == 0) *(float4*)(xh + ((size_t)zl * N_ + i) * 4) = make_float4(p0, p1, p2, p3);
    }
}

// ======== K1: hops + ru gate -> rs, u (4 rows/block, 400 blocks) ========
__global__ void __launch_bounds__(256) k_ru2(
        const float* __restrict__ At, const float* __restrict__ A2t,
        const float* __restrict__ xht,
        const float* __restrict__ x, int t, const float* __restrict__ state,
        const float* __restrict__ Wru, const float* __restrict__ bru,
        float* __restrict__ rs, float* __restrict__ ub) {
    __shared__ float sF[200 * 64];
    __shared__ float a4s[4 * 200], c4s[4 * 200];
    __shared__ float g8[4 * 132];
    __shared__ float xts[8];
    int bx = blockIdx.x;
    int b = bx & 7, i0 = (bx >> 3) * 4;      // XCD-local batches
    int tid = threadIdx.x;
    {
        const float4* stb = (const float4*)(state + (size_t)b * N_ * 64);
        float4* sFv = (float4*)sF;
        for (int idx = tid; idx < 3200; idx += 256) sFv[idx] = stb[idx];
        const float4* Ar = (const float4*)(At + ((size_t)b * N_ + i0) * 200);
        const float4* Cr = (const float4*)(A2t + ((size_t)b * N_ + i0) * 200);
        float4* av = (float4*)a4s; float4* cv = (float4*)c4s;
        for (int idx = tid; idx < 200; idx += 256) { av[idx] = Ar[idx]; cv[idx] = Cr[idx]; }
        if (tid < 8) xts[tid] = x[((size_t)(b * T_ + t) * N_ + i0 + (tid >> 1)) * 2 + (tid & 1)];
        if (tid >= 8 && tid < 24) {
            int l = tid - 8, rr = l >> 2, q = l & 3;
            g8[rr * 132 + ((q < 2) ? q : q + 64)] = xht[((size_t)b * N_ + i0 + rr) * 4 + q];
        }
    }
    __syncthreads();
    if (tid < 64) {   // hop: r=tid>>4 (0..3), cg=tid&15 (4 cols), BOTH matrices
        int r = tid >> 4, cg = tid & 15;
        const float* ar = a4s + r * 200;
        const float* cr = c4s + r * 200;
        float4 accA = make_float4(0.f, 0.f, 0.f, 0.f);
        float4 accC = make_float4(0.f, 0.f, 0.f, 0.f);
        #pragma unroll 2
        for (int jg = 0; jg < 50; ++jg) {
            float4 a4 = *(const float4*)&ar[4 * jg];
            float4 c4 = *(const float4*)&cr[4 * jg];
            const float* fb = &sF[(4 * jg) * 64 + 4 * cg];
            float4 v0 = *(const float4*)fb;
            float4 v1 = *(const float4*)(fb + 64);
            float4 v2 = *(const float4*)(fb + 128);
            float4 v3 = *(const float4*)(fb + 192);
            accA.x += a4.x * v0.x + a4.y * v1.x + a4.z * v2.x + a4.w * v3.x;
            accA.y += a4.x * v0.y + a4.y * v1.y + a4.z * v2.y + a4.w * v3.y;
            accA.z += a4.x * v0.z + a4.y * v1.z + a4.z * v2.z + a4.w * v3.z;
            accA.w += a4.x * v0.w + a4.y * v1.w + a4.z * v2.w + a4.w * v3.w;
            accC.x += c4.x * v0.x + c4.y * v1.x + c4.z * v2.x + c4.w * v3.x;
            accC.y += c4.x * v0.y + c4.y * v1.y + c4.z * v2.y + c4.w * v3.y;
            accC.z += c4.x * v0.z + c4.y * v1.z + c4.z * v2.z + c4.w * v3.z;
            accC.w += c4.x * v0.w + c4.y * v1.w + c4.z * v2.w + c4.w * v3.w;
        }
        float* gr = &g8[r * 132 + 2 + 4 * cg];
        gr[0] = accA.x; gr[1] = accA.y; gr[2] = accA.z; gr[3] = accA.w;
        float* gr2 = gr + 66;
        gr2[0] = accC.x; gr2[1] = accC.y; gr2[2] = accC.z; gr2[3] = accC.w;
    }
    __syncthreads();
    {   // gate: c=tid&127, rq=tid>>7 (0..1) -> rows rq*2+{0,1}
        int c = tid & 127, rq = tid >> 7;
        int r0 = rq * 2, r1 = r0 + 1;
        float bv = bru[c];
        float a0 = bv, a1 = bv;
        #pragma unroll
        for (int k = 0; k < 2; ++k) {
            float wv = Wru[k * 128 + c];
            a0 += xts[r0 * 2 + k] * wv;
            a1 += xts[r1 * 2 + k] * wv;
        }
        #pragma unroll 4
        for (int kg = 0; kg < 16; ++kg) {
            float4 f0 = *(const float4*)&sF[(i0 + r0) * 64 + 4 * kg];
            float4 f1 = *(const float4*)&sF[(i0 + r1) * 64 + 4 * kg];
            const float* Wp = Wru + (2 + 4 * kg) * 128 + c;
            float w0 = Wp[0], w1 = Wp[128], w2 = Wp[256], w3 = Wp[384];
            a0 += f0.x * w0 + f0.y * w1 + f0.z * w2 + f0.w * w3;
            a1 += f1.x * w0 + f1.y * w1 + f1.z * w2 + f1.w * w3;
        }
        #pragma unroll 4
        for (int kg = 0; kg < 33; ++kg) {
            float4 f0 = *(const float4*)&g8[r0 * 132 + 4 * kg];
            float4 f1 = *(const float4*)&g8[r1 * 132 + 4 * kg];
            const float* Wp = Wru + (66 + 4 * kg) * 128 + c;
            float w0 = Wp[0], w1 = Wp[128], w2 = Wp[256], w3 = Wp[384];
            a0 += f0.x * w0 + f0.y * w1 + f0.z * w2 + f0.w * w3;
            a1 += f1.x * w0 + f1.y * w1 + f1.z * w2 + f1.w * w3;
        }
        float v0 = sigm(a0), v1 = sigm(a1);
        size_t gr0 = (size_t)b * N_ + i0 + r0, gr1 = gr0 + 1;
        if (c < 64) {
            rs[gr0 * 64 + c] = v0 * sF[(i0 + r0) * 64 + c];
            rs[gr1 * 64 + c] = v1 * sF[(i0 + r1) * 64 + c];
        } else {
            ub[gr0 * 64 + (c - 64)] = v0;
            ub[gr1 * 64 + (c - 64)] = v1;
        }
    }
}

// ======== K2: hops + cand gate + state update (4 rows/block) ========
__global__ void __launch_bounds__(256) k_cand2(
        const float* __restrict__ At, const float* __restrict__ A2t,
        const float* __restrict__ xht,
        const float* __restrict__ x, int t, const float* __restrict__ rsin,
        const float* __restrict__ Wcd, const float* __restrict__ bcd,
        const float* __restrict__ ub, float* __restrict__ state) {
    __shared__ float sF[200 * 64];
    __shared__ float a4s[4 * 200], c4s[4 * 200];
    __shared__ float g8[4 * 132];
    __shared__ float xts[8];
    int bx = blockIdx.x;
    int b = bx & 7, i0 = (bx >> 3) * 4;      // XCD-local batches
    int tid = threadIdx.x;
    {
        const float4* rbv = (const float4*)(rsin + (size_t)b * N_ * 64);
        float4* sFv = (float4*)sF;
        for (int idx = tid; idx < 3200; idx += 256) sFv[idx] = rbv[idx];
        const float4* Ar = (const float4*)(At + ((size_t)b * N_ + i0) * 200);
        const float4* Cr = (const float4*)(A2t + ((size_t)b * N_ + i0) * 200);
        float4* av = (float4*)a4s; float4* cv = (float4*)c4s;
        for (int idx = tid; idx < 200; idx += 256) { av[idx] = Ar[idx]; cv[idx] = Cr[idx]; }
        if (tid < 8) xts[tid] = x[((size_t)(b * T_ + t) * N_ + i0 + (tid >> 1)) * 2 + (tid & 1)];
        if (tid >= 8 && tid < 24) {
            int l = tid - 8, rr = l >> 2, q = l & 3;
            g8[rr * 132 + ((q < 2) ? q : q + 64)] = xht[((size_t)b * N_ + i0 + rr) * 4 + q];
        }
    }
    __syncthreads();
    if (tid < 64) {   // hop, both matrices
        int r = tid >> 4, cg = tid & 15;
        const float* ar = a4s + r * 200;
        const float* cr = c4s + r * 200;
        float4 accA = make_float4(0.f, 0.f, 0.f, 0.f);
        float4 accC = make_float4(0.f, 0.f, 0.f, 0.f);
        #pragma unroll 2
        for (int jg = 0; jg < 50; ++jg) {
            float4 a4 = *(const float4*)&ar[4 * jg];
            float4 c4 = *(const float4*)&cr[4 * jg];
            const float* fb = &sF[(4 * jg) * 64 + 4 * cg];
            float4 v0 = *(const float4*)fb;
            float4 v1 = *(const float4*)(fb + 64);
            float4 v2 = *(const float4*)(fb + 128);
            float4 v3 = *(const float4*)(fb + 192);
            accA.x += a4.x * v0.x + a4.y * v1.x + a4.z * v2.x + a4.w * v3.x;
            accA.y += a4.x * v0.y + a4.y * v1.y + a4.z * v2.y + a4.w * v3.y;
            accA.z += a4.x * v0.z + a4.y * v1.z + a4.z * v2.z + a4.w * v3.z;
            accA.w += a4.x * v0.w + a4.y * v1.w + a4.z * v2.w + a4.w * v3.w;
            accC.x += c4.x * v0.x + c4.y * v1.x + c4.z * v2.x + c4.w * v3.x;
            accC.y += c4.x * v0.y + c4.y * v1.y + c4.z * v2.y + c4.w * v3.y;
            accC.z += c4.x * v0.z + c4.y * v1.z + c4.z * v2.z + c4.w * v3.z;
            accC.w += c4.x * v0.w + c4.y * v1.w + c4.z * v2.w + c4.w * v3.w;
        }
        float* gr = &g8[r * 132 + 2 + 4 * cg];
        gr[0] = accA.x; gr[1] = accA.y; gr[2] = accA.z; gr[3] = accA.w;
        float* gr2 = gr + 66;
        gr2[0] = accC.x; gr2[1] = accC.y; gr2[2] = accC.z; gr2[3] = accC.w;
    }
    __syncthreads();
    {   // gate: r=tid>>6 (0..3), c=tid&63 — one output each
        int c = tid & 63, r = tid >> 6;
        float a0 = bcd[c];
        #pragma unroll
        for (int k = 0; k < 2; ++k) a0 += xts[r * 2 + k] * Wcd[k * 64 + c];
        #pragma unroll 4
        for (int kg = 0; kg < 16; ++kg) {
            float4 f0 = *(const float4*)&sF[(i0 + r) * 64 + 4 * kg];
            const float* Wp = Wcd + (2 + 4 * kg) * 64 + c;
            a0 += f0.x * Wp[0] + f0.y * Wp[64] + f0.z * Wp[128] + f0.w * Wp[192];
        }
        #pragma unroll 4
        for (int kg = 0; kg < 33; ++kg) {
            float4 f0 = *(const float4*)&g8[r * 132 + 4 * kg];
            const float* Wp = Wcd + (66 + 4 * kg) * 64 + c;
            a0 += f0.x * Wp[0] + f0.y * Wp[64] + f0.z * Wp[128] + f0.w * Wp[192];
        }
        size_t gr = (size_t)b * N_ + i0 + r;
        float cnd = tanhf(a0);
        float u = ub[gr * 64 + c];
        float st = state[gr * 64 + c];
        state[gr * 64 + c] = u * st + (1.f - u) * cnd;
    }
}

// ======== pred head ========
__global__ void __launch_bounds__(64) k_pred(
        const float* __restrict__ state,
        const float* __restrict__ Wp1, const float* __restrict__ bp1,
        const float* __restrict__ Wp2, const float* __restrict__ bp2,
        float* __restrict__ out) {
    __shared__ float st[64];
    int row = blockIdx.x;
    int tid = threadIdx.x;
    st[tid] = state[row * 64 + tid];
    __syncthreads();
    float acc = bp1[tid];
    #pragma unroll 8
    for (int a = 0; a < 64; ++a) acc += st[a] * Wp1[a * 64 + tid];
    acc = acc > 0.f ? acc : 0.01f * acc;
    float v = acc * Wp2[tid];
    #pragma unroll
    for (int off = 32; off > 0; off >>= 1) v += __shfl_down(v, off);
    if (tid == 0) out[row] = v + bp2[0];
}

extern "C" void kernel_launch(void* const* d_in, const int* in_sizes, int n_in,
                              void* d_out, int out_size, void* d_ws, size_t ws_size,
                              hipStream_t stream) {
    const float* x    = (const float*)d_in[0];
    const float* nf   = (const float*)d_in[1];
    const float* Ws2d = (const float*)d_in[2];
    const float* bs2d = (const float*)d_in[3];
    const float* Wrz  = (const float*)d_in[4];
    const float* brz  = (const float*)d_in[5];
    const float* Wh   = (const float*)d_in[6];
    const float* bh   = (const float*)d_in[7];
    const float* Wc2  = (const float*)d_in[8];
    const float* bc2  = (const float*)d_in[9];
    const float* Wc1  = (const float*)d_in[10];
    const float* bc1  = (const float*)d_in[11];
    const float* Wm2  = (const float*)d_in[12];
    const float* bm2  = (const float*)d_in[13];
    const float* Wm1  = (const float*)d_in[14];
    const float* bm1  = (const float*)d_in[15];
    const float* Wru  = (const float*)d_in[16];
    const float* bru  = (const float*)d_in[17];
    const float* Wcand= (const float*)d_in[18];
    const float* bcand= (const float*)d_in[19];
    const float* Wp1  = (const float*)d_in[20];
    const float* bp1  = (const float*)d_in[21];
    const float* Wp2  = (const float*)d_in[22];
    const float* bp2  = (const float*)d_in[23];
    float* out = (float*)d_out;

    float* ws = (float*)d_ws;
    const size_t PQ = (size_t)T_ * R_ * 32;
    float* Pc = ws;
    float* Qc = Pc + PQ;
    float* Pm = Qc + PQ;
    float* Qm = Pm + PQ;

    const size_t A2F = (size_t)96 * NN_;
    const size_t XHF = (size_t)96 * N_ * 4;
    const size_t FULL_NEED = (A2F + XHF + 3 * (size_t)R_ * 64) * 4;
    bool full = ws_size >= FULL_NEED;

    const float* Aall = out + R_;

    if (full) {
        float* A2base = ws;                  // aliases dead P/Q after k_pairall
        float* xhbase = ws + A2F;
        float* state  = xhbase + XHF;
        float* rs     = state + (size_t)R_ * 64;
        float* ub     = rs + (size_t)R_ * 64;

        k_dyall<<<400, 256, 0, stream>>>(x, nf, Ws2d, bs2d, Wrz, brz, Wh, bh,
                                         Wc2, Wm2, bc2, bm2, Pc, Qc, Pm, Qm, state);
        k_pairall<<<dim3(13, 13, 96), dim3(16, 16), 0, stream>>>(
            Pc, Qc, Pm, Qm, Wc1, bc1, Wm1, bm1, out);
        k_a2<<<96 * 16, 256, 0, stream>>>(Aall, A2base, 96);
        k_xh<<<96, 256, 0, stream>>>(Aall, A2base, x, 0, xhbase);

        for (int t = 0; t < T_; ++t) {
            const float* At  = Aall + (size_t)t * 8 * NN_;
            const float* A2t = A2base + (size_t)t * 8 * NN_;
            const float* xht = xhbase + (size_t)t * 8 * N_ * 4;
            k_ru2  <<<400, 256, 0, stream>>>(At, A2t, xht, x, t, state, Wru, bru, rs, ub);
            k_cand2<<<400, 256, 0, stream>>>(At, A2t, xht, x, t, rs, Wcand, bcand, ub, state);
        }
        k_pred<<<R_, 64, 0, stream>>>(state, Wp1, bp1, Wp2, bp2, out);
    } else {
        float* A2base = ws + 4 * PQ;
        float* xhbase = A2base + (size_t)8 * NN_;
        float* state  = xhbase + (size_t)8 * N_ * 4;
        float* rs     = state + (size_t)R_ * 64;
        float* ub     = rs + (size_t)R_ * 64;

        k_dyall<<<400, 256, 0, stream>>>(x, nf, Ws2d, bs2d, Wrz, brz, Wh, bh,
                                         Wc2, Wm2, bc2, bm2, Pc, Qc, Pm, Qm, state);
        k_pairall<<<dim3(13, 13, 96), dim3(16, 16), 0, stream>>>(
            Pc, Qc, Pm, Qm, Wc1, bc1, Wm1, bm1, out);
        for (int t = 0; t < T_; ++t) {
            const float* At = Aall + (size_t)t * 8 * NN_;
            k_a2<<<8 * 16, 256, 0, stream>>>(At, A2base, 8);
            k_xh<<<8, 256, 0, stream>>>(At, A2base, x, t * 8, xhbase);
            k_ru2  <<<400, 256, 0, stream>>>(At, A2base, xhbase, x, t, state, Wru, bru, rs, ub);
            k_cand2<<<400, 256, 0, stream>>>(At, A2base, xhbase, x, t, rs, Wcand, bcand, ub, state);
        }
        k_pred<<<R_, 64, 0, stream>>>(state, Wp1, bp1, Wp2, bp2, out);
    }
}